// Round 1
// baseline (1495.888 us; speedup 1.0000x reference)
//
#include <hip/hip_runtime.h>

// Problem constants (from setup_inputs):
//   x:        [B=2, C=16, N=512, Ht=64, Wt=64] float32
//   quad_idx: [Ho=1024, Wo=1024] int32
//   tex_uv:   [Ho=1024, Wo=1024, 2] float32
//   out:      [B, C, Ho, Wo] float32
#define HT 64
#define WT 64
#define NTEX 512
#define HO 1024
#define WO 1024
#define BC 32                       // B*C channel slabs
#define CH_STRIDE (NTEX * HT * WT)  // 2,097,152 floats per (b,c) slab
#define NPIX (HO * WO)

__global__ __launch_bounds__(256) void ResampleFromUV_kernel(
    const float* __restrict__ x,
    const int*   __restrict__ quad_idx,
    const float* __restrict__ tex_uv,
    float*       __restrict__ out)
{
    const int pix = blockIdx.x * blockDim.x + threadIdx.x;
    if (pix >= NPIX) return;

    const int n = quad_idx[pix];
    const float2 uv = reinterpret_cast<const float2*>(tex_uv)[pix];

    const float u = uv.x * (float)(WT - 1);
    const float v = uv.y * (float)(HT - 1);

    int x0 = (int)floorf(u);
    int y0 = (int)floorf(v);
    // Clamp to [0, Wt-2] so x1 = x0+1 is always valid. With wu = u - x0 this
    // is algebraically identical to the reference's separate x0/x1 clamps
    // (at u == Wt-1 exactly, full weight lands on texel Wt-1 either way).
    x0 = min(max(x0, 0), WT - 2);
    y0 = min(max(y0, 0), HT - 2);

    const float wu = u - (float)x0;
    const float wv = v - (float)y0;
    const float w00 = (1.0f - wu) * (1.0f - wv);
    const float w01 = wu * (1.0f - wv);
    const float w10 = (1.0f - wu) * wv;
    const float w11 = wu * wv;

    const int off0 = n * (HT * WT) + y0 * WT + x0;  // row y0, texels x0..x0+1
    const int off1 = off0 + WT;                     // row y1

    const float* __restrict__ p = x;
    float* __restrict__ o = out + pix;

    #pragma unroll 8
    for (int ch = 0; ch < BC; ++ch) {
        // 8-byte row-pair loads; memcpy keeps correctness even if the
        // element offset is odd (4-byte aligned only).
        float2 r0, r1;
        __builtin_memcpy(&r0, p + off0, 8);
        __builtin_memcpy(&r1, p + off1, 8);
        o[0] = w00 * r0.x + w01 * r0.y + w10 * r1.x + w11 * r1.y;
        p += CH_STRIDE;
        o += NPIX;
    }
}

extern "C" void kernel_launch(void* const* d_in, const int* in_sizes, int n_in,
                              void* d_out, int out_size, void* d_ws, size_t ws_size,
                              hipStream_t stream) {
    const float* x        = (const float*)d_in[0];
    const int*   quad_idx = (const int*)d_in[1];
    const float* tex_uv   = (const float*)d_in[2];
    float*       out      = (float*)d_out;

    const int threads = 256;
    const int blocks = NPIX / threads;  // 4096
    ResampleFromUV_kernel<<<blocks, threads, 0, stream>>>(x, quad_idx, tex_uv, out);
}

// Round 2
// 1437.729 us; speedup vs baseline: 1.0405x; 1.0405x over previous
//
#include <hip/hip_runtime.h>

// Problem constants (from setup_inputs):
//   x:        [B=2, C=16, N=512, Ht=64, Wt=64] float32   (256 MB atlas)
//   quad_idx: [Ho=1024, Wo=1024] int32
//   tex_uv:   [Ho=1024, Wo=1024, 2] float32
//   out:      [B, C, Ho, Wo] float32                      (134 MB)
#define HT 64
#define WT 64
#define NTEX 512
#define HO 1024
#define WO 1024
#define BC 32                       // B*C channel slabs
#define CH_STRIDE (NTEX * HT * WT)  // 8 MB per (b,c) slab (in floats)
#define NPIX (HO * WO)

// Channels per chunk: active gather footprint = CH * 8 MB. CH=8 -> 64 MB,
// comfortably inside the 256 MB L3 so gather re-reads (16x avg reuse) are
// absorbed by Infinity Cache instead of hitting HBM.
#define CH 8
#define NCHUNK (BC / CH)

__global__ __launch_bounds__(256) void ResampleFromUV_kernel(
    const float* __restrict__ x,
    const int*   __restrict__ quad_idx,
    const float* __restrict__ tex_uv,
    float*       __restrict__ out)
{
    const int pix   = blockIdx.x * blockDim.x + threadIdx.x;
    const int chunk = blockIdx.y;
    if (pix >= NPIX) return;

    const int n = quad_idx[pix];
    const float2 uv = reinterpret_cast<const float2*>(tex_uv)[pix];

    const float u = uv.x * (float)(WT - 1);
    const float v = uv.y * (float)(HT - 1);

    int x0 = (int)floorf(u);
    int y0 = (int)floorf(v);
    // Clamp to [0, Wt-2] so x1 = x0+1 is always valid; wu = u - x0 makes this
    // algebraically identical to the reference's separate x0/x1 clamps.
    x0 = min(max(x0, 0), WT - 2);
    y0 = min(max(y0, 0), HT - 2);

    const float wu = u - (float)x0;
    const float wv = v - (float)y0;
    const float w00 = (1.0f - wu) * (1.0f - wv);
    const float w01 = wu * (1.0f - wv);
    const float w10 = (1.0f - wu) * wv;
    const float w11 = wu * wv;

    const int off0 = n * (HT * WT) + y0 * WT + x0;  // row y0, texels x0..x0+1
    const int off1 = off0 + WT;                     // row y1

    const float* __restrict__ p = x + (size_t)chunk * CH * CH_STRIDE;
    float* __restrict__ o = out + (size_t)chunk * CH * NPIX + pix;

    #pragma unroll
    for (int ch = 0; ch < CH; ++ch) {
        float2 r0, r1;
        __builtin_memcpy(&r0, p + off0, 8);   // 8-byte row-pair loads
        __builtin_memcpy(&r1, p + off1, 8);
        const float val = w00 * r0.x + w01 * r0.y + w10 * r1.x + w11 * r1.y;
        // Non-temporal: keep the streaming output from evicting atlas lines
        // out of L2/L3 (the whole win of this round is L3-resident gathers).
        __builtin_nontemporal_store(val, o);
        p += CH_STRIDE;
        o += NPIX;
    }
}

extern "C" void kernel_launch(void* const* d_in, const int* in_sizes, int n_in,
                              void* d_out, int out_size, void* d_ws, size_t ws_size,
                              hipStream_t stream) {
    const float* x        = (const float*)d_in[0];
    const int*   quad_idx = (const int*)d_in[1];
    const float* tex_uv   = (const float*)d_in[2];
    float*       out      = (float*)d_out;

    const int threads = 256;
    dim3 grid(NPIX / threads, NCHUNK);  // chunk in y: dispatched after all x of
                                        // previous y -> temporal channel locality
    ResampleFromUV_kernel<<<grid, dim3(threads), 0, stream>>>(x, quad_idx, tex_uv, out);
}

// Round 3
// 1261.338 us; speedup vs baseline: 1.1860x; 1.1398x over previous
//
#include <hip/hip_runtime.h>

// x:        [B=2, C=16, N=512, Ht=64, Wt=64] float32  (256 MB atlas)
// quad_idx: [Ho=1024, Wo=1024] int32
// tex_uv:   [Ho=1024, Wo=1024, 2] float32
// out:      [B, C, Ho, Wo] float32                    (134 MB)
#define HT 64
#define WT 64
#define NTEX 512
#define HO 1024
#define WO 1024
#define BC 32
#define SLAB (HT * WT)              // 4096 floats = 16 KB per (channel, texture)
#define NPIX (HO * WO)

// ---------------- ws layout ----------------
// [0, 2048)        hist[512]   u32
// [2048, 4100)     base[513]   u32
// [4608, 6656)     cursor[512] u32
// [8192, 8M+8192)  meta[NPIX]  uint2  {pix<<12|off, wv16<<16|wu16}
#define WS_HIST   0
#define WS_BASE   2048
#define WS_CURSOR 4608
#define WS_META   8192
#define WS_NEEDED ((size_t)(8u << 20) + 16384)

// ---- K1: per-block LDS histogram of quad_idx -> global hist ----
__global__ __launch_bounds__(256) void k_hist(const int* __restrict__ quad_idx,
                                              unsigned* __restrict__ hist) {
    __shared__ unsigned h[NTEX];
    for (int i = threadIdx.x; i < NTEX; i += 256) h[i] = 0;
    __syncthreads();
    const int pix = blockIdx.x * 256 + threadIdx.x;
    atomicAdd(&h[quad_idx[pix]], 1u);
    __syncthreads();
    for (int i = threadIdx.x; i < NTEX; i += 256) {
        unsigned v = h[i];
        if (v) atomicAdd(&hist[i], v);
    }
}

// ---- K2: exclusive scan of 512 bins (single block) ----
__global__ __launch_bounds__(512) void k_scan(const unsigned* __restrict__ hist,
                                              unsigned* __restrict__ base,
                                              unsigned* __restrict__ cursor) {
    __shared__ unsigned t[NTEX];
    const int i = threadIdx.x;
    const unsigned h = hist[i];
    t[i] = h;
    __syncthreads();
    for (int s = 1; s < NTEX; s <<= 1) {
        unsigned v = (i >= s) ? t[i - s] : 0u;
        __syncthreads();
        t[i] += v;
        __syncthreads();
    }
    const unsigned excl = t[i] - h;
    base[i] = excl;
    cursor[i] = excl;
    if (i == NTEX - 1) base[NTEX] = t[i];
}

// ---- K3: build compacted per-bucket meta records ----
__global__ __launch_bounds__(256) void k_meta(const int* __restrict__ quad_idx,
                                              const float* __restrict__ tex_uv,
                                              unsigned* __restrict__ cursor,
                                              uint2* __restrict__ meta) {
    const int pix = blockIdx.x * 256 + threadIdx.x;
    const int n = quad_idx[pix];
    const float2 uv = reinterpret_cast<const float2*>(tex_uv)[pix];

    const float u = uv.x * (float)(WT - 1);
    const float v = uv.y * (float)(HT - 1);
    int x0 = (int)floorf(u);
    int y0 = (int)floorf(v);
    x0 = min(max(x0, 0), WT - 2);   // x1=x0+1 valid; wu=u-x0 matches reference clamp
    y0 = min(max(y0, 0), HT - 2);
    const float wu = u - (float)x0;
    const float wv = v - (float)y0;

    const unsigned off = (unsigned)(y0 * WT + x0);               // 12 bits (<=4094)
    const unsigned key = ((unsigned)pix << 12) | off;
    const unsigned wu16 = (unsigned)__float2int_rn(wu * 65535.0f);
    const unsigned wv16 = (unsigned)__float2int_rn(wv * 65535.0f);

    const unsigned rank = atomicAdd(&cursor[n], 1u);
    meta[rank] = make_uint2(key, wu16 | (wv16 << 16));
}

// ---- K4: per-(bucket, channel) block: LDS-stage slab, resolve taps ----
// Block decode pins channel%8 to blockIdx%8 (XCD round-robin): each XCD works
// one channel at a time -> its 4 MB out-slab fits its own L2 -> the ~16
// scattered 4B writes per 64B out-line merge before one eviction.
__global__ __launch_bounds__(256) void k_main(const float* __restrict__ x,
                                              const unsigned* __restrict__ base,
                                              const uint2* __restrict__ meta,
                                              float* __restrict__ out) {
    __shared__ float s[SLAB];

    const int b = blockIdx.x;        // 0..16383
    const int xcd = b & 7;
    const int i = b >> 3;            // 0..2047
    const int cgrp = i >> 9;         // 0..3
    const int n = i & 511;           // bucket / texture id
    const int c = cgrp * 8 + xcd;    // channel slab 0..31

    // coalesced slab load: 4096 floats as 1024 float4
    const float4* __restrict__ slab4 =
        reinterpret_cast<const float4*>(x + ((size_t)c * NTEX + n) * SLAB);
    float4* s4 = reinterpret_cast<float4*>(s);
    #pragma unroll
    for (int j = 0; j < 4; ++j)
        s4[threadIdx.x + 256 * j] = slab4[threadIdx.x + 256 * j];
    __syncthreads();

    const unsigned lo = base[n];
    const unsigned hi = base[n + 1];
    const uint2* __restrict__ m = meta + lo;
    const unsigned cnt = hi - lo;
    float* __restrict__ o = out + (size_t)c * NPIX;

    for (unsigned j = threadIdx.x; j < cnt; j += 256) {
        const uint2 r = m[j];
        const unsigned off = r.x & 4095u;
        const unsigned pix = r.x >> 12;
        const float wu = (float)(r.y & 65535u) * (1.0f / 65535.0f);
        const float wv = (float)(r.y >> 16) * (1.0f / 65535.0f);

        const float g00 = s[off];
        const float g01 = s[off + 1];
        const float g10 = s[off + WT];
        const float g11 = s[off + WT + 1];

        const float top = g00 + wu * (g01 - g00);
        const float bot = g10 + wu * (g11 - g10);
        o[pix] = top + wv * (bot - top);   // normal store: let L2 merge lines
    }
}

// ---- fallback (round-2 kernel) if ws too small ----
__global__ __launch_bounds__(256) void k_direct(const float* __restrict__ x,
                                                const int* __restrict__ quad_idx,
                                                const float* __restrict__ tex_uv,
                                                float* __restrict__ out) {
    const int pix = blockIdx.x * blockDim.x + threadIdx.x;
    const int chunk = blockIdx.y;
    const int n = quad_idx[pix];
    const float2 uv = reinterpret_cast<const float2*>(tex_uv)[pix];
    const float u = uv.x * (float)(WT - 1);
    const float v = uv.y * (float)(HT - 1);
    int x0 = (int)floorf(u), y0 = (int)floorf(v);
    x0 = min(max(x0, 0), WT - 2);
    y0 = min(max(y0, 0), HT - 2);
    const float wu = u - (float)x0, wv = v - (float)y0;
    const float w00 = (1.f - wu) * (1.f - wv), w01 = wu * (1.f - wv);
    const float w10 = (1.f - wu) * wv, w11 = wu * wv;
    const int off0 = n * SLAB + y0 * WT + x0, off1 = off0 + WT;
    const float* p = x + (size_t)chunk * 8 * NTEX * SLAB;
    float* o = out + (size_t)chunk * 8 * NPIX + pix;
    #pragma unroll
    for (int ch = 0; ch < 8; ++ch) {
        float2 r0, r1;
        __builtin_memcpy(&r0, p + off0, 8);
        __builtin_memcpy(&r1, p + off1, 8);
        o[0] = w00 * r0.x + w01 * r0.y + w10 * r1.x + w11 * r1.y;
        p += (size_t)NTEX * SLAB;
        o += NPIX;
    }
}

extern "C" void kernel_launch(void* const* d_in, const int* in_sizes, int n_in,
                              void* d_out, int out_size, void* d_ws, size_t ws_size,
                              hipStream_t stream) {
    const float* x        = (const float*)d_in[0];
    const int*   quad_idx = (const int*)d_in[1];
    const float* tex_uv   = (const float*)d_in[2];
    float*       out      = (float*)d_out;

    if (ws_size < WS_NEEDED) {  // ws_size constant per session -> same work every call
        dim3 grid(NPIX / 256, 4);
        k_direct<<<grid, 256, 0, stream>>>(x, quad_idx, tex_uv, out);
        return;
    }

    char* ws = (char*)d_ws;
    unsigned* hist   = (unsigned*)(ws + WS_HIST);
    unsigned* base   = (unsigned*)(ws + WS_BASE);
    unsigned* cursor = (unsigned*)(ws + WS_CURSOR);
    uint2*    meta   = (uint2*)(ws + WS_META);

    hipMemsetAsync(hist, 0, NTEX * sizeof(unsigned), stream);
    k_hist<<<NPIX / 256, 256, 0, stream>>>(quad_idx, hist);
    k_scan<<<1, 512, 0, stream>>>(hist, base, cursor);
    k_meta<<<NPIX / 256, 256, 0, stream>>>(quad_idx, tex_uv, cursor, meta);
    k_main<<<NTEX * BC, 256, 0, stream>>>(x, base, meta, out);
}